// Round 6
// baseline (2553.608 us; speedup 1.0000x reference)
//
#include <hip/hip_runtime.h>

#define N_PTS   16384
#define M_CENT  1024
#define K_SMP   32
#define C_FEAT  64
#define NCELL   512

using bf16x8 = __attribute__((ext_vector_type(8))) short;
using s16x4  = __attribute__((ext_vector_type(4))) short;
using f32x4  = __attribute__((ext_vector_type(4))) float;

__device__ inline short f2bf(float f) {            // f32 -> bf16 RNE
    unsigned u = __float_as_uint(f);
    u += 0x7fffu + ((u >> 16) & 1u);
    return (short)(u >> 16);
}

// 64-bit xor shuffle from two 32-bit shuffles
__device__ inline unsigned long long shfl_xor_u64(unsigned long long v, int m) {
    int lo = (int)(unsigned int)v;
    int hi = (int)(unsigned int)(v >> 32);
    lo = __shfl_xor(lo, m);
    hi = __shfl_xor(hi, m);
    return ((unsigned long long)(unsigned int)hi << 32) | (unsigned int)lo;
}

// ---------------------------------------------------------------------------
// Hilbert cell id (8x8x8 = 512 cells). Consecutive Hilbert cells are always
// face-adjacent -> tight per-lane bboxes -> good FPS pruning. Order affects
// only speed, never correctness.
__device__ inline int hcell_of(float x, float y, float z) {
    int xi = (int)(x * 8.0f); xi = xi < 0 ? 0 : (xi > 7 ? 7 : xi);
    int yi = (int)(y * 8.0f); yi = yi < 0 ? 0 : (yi > 7 ? 7 : yi);
    int zi = (int)(z * 8.0f); zi = zi < 0 ? 0 : (zi > 7 ? 7 : zi);
    unsigned X[3] = {(unsigned)xi, (unsigned)yi, (unsigned)zi};
#pragma unroll
    for (unsigned Q = 4; Q > 1; Q >>= 1) {
        unsigned P = Q - 1;
#pragma unroll
        for (int i = 0; i < 3; ++i) {
            if (X[i] & Q) X[0] ^= P;
            else { unsigned t = (X[0] ^ X[i]) & P; X[0] ^= t; X[i] ^= t; }
        }
    }
    X[1] ^= X[0]; X[2] ^= X[1];
    unsigned t = 0;
#pragma unroll
    for (unsigned Q = 4; Q > 1; Q >>= 1)
        if (X[2] & Q) t ^= Q - 1;
    X[0] ^= t; X[1] ^= t; X[2] ^= t;
    int h = 0;
#pragma unroll
    for (int q = 2; q >= 0; --q)
        h = (h << 3) | (((X[0] >> q) & 1) << 2) | (((X[1] >> q) & 1) << 1) | ((X[2] >> q) & 1);
    return h;
}

// ---------------------------------------------------------------------------
__global__ __launch_bounds__(1024) void hist_kernel(
    const float* __restrict__ xyz, int* __restrict__ ghist)
{
    __shared__ int h[NCELL];
    const int b = blockIdx.x, tid = threadIdx.x;
    if (tid < NCELL) h[tid] = 0;
    __syncthreads();
    const float* P = xyz + (size_t)b * N_PTS * 3;
    for (int i = 0; i < 16; ++i) {
        const int p = tid + (i << 10);
        atomicAdd(&h[hcell_of(P[p*3], P[p*3+1], P[p*3+2])], 1);
    }
    __syncthreads();
    if (tid < NCELL) ghist[b * NCELL + tid] = h[tid];
}

__global__ __launch_bounds__(NCELL) void scan_kernel(
    const int* __restrict__ ghist, int* __restrict__ gbase)
{
    __shared__ int h[NCELL];
    const int b = blockIdx.x, t = threadIdx.x;
    h[t] = ghist[b * NCELL + t];
    __syncthreads();
    int s = 0;
    for (int i = 0; i < t; ++i) s += h[i];
    gbase[b * NCELL + t] = s;
}

__global__ __launch_bounds__(1024) void scatter_kernel(
    const float* __restrict__ xyz, int* __restrict__ gbase,
    float4* __restrict__ gsxyz)
{
    const int b = blockIdx.x, tid = threadIdx.x;
    const float* P = xyz + (size_t)b * N_PTS * 3;
    for (int i = 0; i < 16; ++i) {
        const int p = tid + (i << 10);
        float x = P[p*3], y = P[p*3+1], z = P[p*3+2];
        int c = hcell_of(x, y, z);
        int pos = atomicAdd(&gbase[b * NCELL + c], 1);
        gsxyz[(size_t)b * N_PTS + pos] = make_float4(x, y, z, __int_as_float(p));
    }
}

// ---------------------------------------------------------------------------
// FPS, bit-exact pruned. __launch_bounds__(1024, 4): 4 waves/EU -> 128-VGPR
// cap, so the 80-register point state (px/py/pz/mind/klo) lives ENTIRELY in
// registers. At the default 64-VGPR cap the compiler spilled these arrays to
// scratch; every inner-loop access was a global-latency round trip (r5 PMC:
// WRITE_SIZE 368KB vs 64KB of real output, VGPR_Count=64 < live set).
__global__ __launch_bounds__(1024, 4) void fps_kernel(
    const float* __restrict__ xyz,
    const float4* __restrict__ gsxyz,
    float* __restrict__ newxyz_out,
    float* __restrict__ idxf_out)
{
#pragma clang fp contract(off)
    const int b = blockIdx.x, tid = threadIdx.x;
    const int wid = tid >> 6, lane = tid & 63;
    const float4* S = gsxyz + (size_t)b * N_PTS;

    float px[16], py[16], pz[16], mind[16];
    unsigned klo[16];
    float lox = 1e30f, hix = -1e30f, loy = 1e30f, hiy = -1e30f, loz = 1e30f, hiz = -1e30f;
#pragma unroll
    for (int i = 0; i < 16; ++i) {
        const float4 v = S[tid * 16 + i];
        px[i] = v.x; py[i] = v.y; pz[i] = v.z;
        const int orig = __float_as_int(v.w);
        klo[i] = ((unsigned)(16383 - orig) << 16) | (unsigned)(tid * 16 + i);
        mind[i] = __int_as_float(0x7f800000);
        lox = fminf(lox, v.x); hix = fmaxf(hix, v.x);
        loy = fminf(loy, v.y); hiy = fmaxf(hiy, v.y);
        loz = fminf(loz, v.z); hiz = fmaxf(hiz, v.z);
    }

    __shared__ unsigned long long wkeys[2][16];   // parity double-buffer
    __shared__ float4 wcoord[2][16];

    const float* P = xyz + (size_t)b * N_PTS * 3;
    float cx = P[0], cy = P[1], cz = P[2];
    if (tid == 0) {
        idxf_out[b * M_CENT] = 0.0f;
        newxyz_out[(b * M_CENT) * 3 + 0] = cx;
        newxyz_out[(b * M_CENT) * 3 + 1] = cy;
        newxyz_out[(b * M_CENT) * 3 + 2] = cz;
    }
    __syncthreads();

    unsigned long long bkey = 0x7f80000000000000ull;   // lane max-mind = +inf
    unsigned long long wkey = 0x7f80000000000000ull;   // wave max-mind = +inf
    float cwx = 0.f, cwy = 0.f, cwz = 0.f;             // owner-lane coord cache

    for (int j = 1; j < M_CENT; ++j) {
        const int par = j & 1;
        // lane-level conservative reject (bit-exact: fminf(mind,d)==mind
        // whenever d>=mind; margin 1.5e-5 >> worst-case f32 rounding)
        float tx = fmaxf(fmaxf(lox - cx, cx - hix), 0.0f);
        float ty = fmaxf(fmaxf(loy - cy, cy - hiy), 0.0f);
        float tz = fmaxf(fmaxf(loz - cz, cz - hiz), 0.0f);
        float lb = (tx * tx + ty * ty) + tz * tz;
        float lmax = __uint_as_float((unsigned)(bkey >> 32));
        bool need = (lb * 0.999985f) < lmax;

        if (__any(need)) {
            // pass 1: distances + value-only max
            float bv = -1.0f;
#pragma unroll
            for (int i = 0; i < 16; ++i) {
                float dx = px[i] - cx;
                float dy = py[i] - cy;
                float dz = pz[i] - cz;
                float xx = dx * dx, yy = dy * dy, zz = dz * dz;
                float d  = (xx + yy) + zz;            // numpy order, no fma
                float mn = fminf(mind[i], d);
                mind[i] = mn;
                bv = fmaxf(bv, mn);
            }
            // pass 2: tie-break (max klo = smallest original idx) + coords
            unsigned bk = 0u;
            float wxx = 0.f, wyy = 0.f, wzz = 0.f;
#pragma unroll
            for (int i = 0; i < 16; ++i) {
                bool c = (mind[i] == bv) && (klo[i] >= bk);
                bk  = c ? klo[i] : bk;
                wxx = c ? px[i]  : wxx;
                wyy = c ? py[i]  : wyy;
                wzz = c ? pz[i]  : wzz;
            }
            bkey = ((unsigned long long)__float_as_uint(bv) << 32) | bk;
            cwx = wxx; cwy = wyy; cwz = wzz;

            unsigned long long w = bkey;
#pragma unroll
            for (int off = 32; off >= 1; off >>= 1) {
                unsigned long long o = shfl_xor_u64(w, off);
                if (o > w) w = o;
            }
            wkey = w;
        }
        // unique owner lane (keys are unique) publishes key + coords
        if (bkey == wkey) {
            wkeys[par][wid]  = wkey;
            wcoord[par][wid] = make_float4(cwx, cwy, cwz, 0.f);
        }
        __syncthreads();

        unsigned long long k2 = wkeys[par][lane & 15];
#pragma unroll
        for (int off = 8; off >= 1; off >>= 1) {
            unsigned long long o = shfl_xor_u64(k2, off);
            if (o > k2) k2 = o;
        }
        const unsigned int kl = (unsigned int)k2;
        const int winw = (int)((kl & 0xFFFFu) >> 10);
        const float4 wc = wcoord[par][winw];          // broadcast LDS read
        cx = wc.x; cy = wc.y; cz = wc.z;
        if (tid == 0) {
            const int orig = 16383 - (int)(kl >> 16);
            idxf_out[b * M_CENT + j] = (float)orig;
            newxyz_out[(b * M_CENT + j) * 3 + 0] = cx;
            newxyz_out[(b * M_CENT + j) * 3 + 1] = cy;
            newxyz_out[(b * M_CENT + j) * 3 + 2] = cz;
        }
        // no second barrier: parity alternates, and reaching the same parity
        // again requires passing the next barrier, which happens-after all
        // reads above.
    }
}

// ---------------------------------------------------------------------------
__global__ __launch_bounds__(256) void ball_kernel(
    const float* __restrict__ xyz,
    const float* __restrict__ newxyz,
    int* __restrict__ nidx)
{
#pragma clang fp contract(off)
    const float R2 = (float)(0.1 * 0.1);
    const int gw   = blockIdx.x * 4 + (threadIdx.x >> 6);
    const int lane = threadIdx.x & 63;
    const int b    = gw >> 10;
    const float* P = xyz + (size_t)b * N_PTS * 3;
    const float cx = newxyz[gw * 3 + 0];
    const float cy = newxyz[gw * 3 + 1];
    const float cz = newxyz[gw * 3 + 2];
    int* out = nidx + gw * K_SMP;

    int cnt = 0, first = -1;
    for (int base = 0; base < N_PTS; base += 64) {
        const int n = base + lane;
        float dx = P[n * 3 + 0] - cx;
        float dy = P[n * 3 + 1] - cy;
        float dz = P[n * 3 + 2] - cz;
        float xx = dx * dx, yy = dy * dy, zz = dz * dz;
        float d2 = (xx + yy) + zz;
        bool inb = d2 < R2;
        unsigned long long mask = __ballot(inb);
        if (mask) {
            if (first < 0) first = base + __ffsll(mask) - 1;
            int before = __popcll(mask & ((1ull << lane) - 1ull));
            int slot = cnt + before;
            if (inb && slot < K_SMP) out[slot] = n;
            cnt += __popcll(mask);
            if (cnt >= K_SMP) break;
        }
    }
    for (int s = cnt + lane; s < K_SMP; s += 64) out[s] = first;
}

// ---------------------------------------------------------------------------
// Weight prep: f32 (OC,IC) -> bf16 (OC,ICP). remap=1 reorders input channels
// from [xyz(3), feat(64)] to [feat(64), xyz(3), pad] to match Xt layout.
__global__ void prep_w(const float* __restrict__ src, short* __restrict__ dst,
                       int OC, int IC, int ICP, int remap)
{
    int i = blockIdx.x * 256 + threadIdx.x;
    if (i >= OC * ICP) return;
    int oc = i / ICP, ic = i - oc * ICP;
    float v = 0.0f;
    if (remap) {
        if (ic < 64)      v = src[oc * IC + 3 + ic];
        else if (ic < 67) v = src[oc * IC + (ic - 64)];
    } else if (ic < IC)   v = src[oc * IC + ic];
    dst[i] = f2bf(v);
}

// feat (B,64,N) -> featT (B,N,64)
__global__ __launch_bounds__(256) void tfeat_kernel(
    const float* __restrict__ feat, float* __restrict__ featT)
{
    __shared__ float t[64][65];
    const int b = blockIdx.y;
    const int n0 = blockIdx.x * 64;
    for (int it = 0; it < 16; ++it) {
        int idx = it * 256 + threadIdx.x;
        int c = idx >> 6, n = idx & 63;
        t[c][n] = feat[((size_t)b * 64 + c) * N_PTS + n0 + n];
    }
    __syncthreads();
    for (int it = 0; it < 16; ++it) {
        int idx = it * 256 + threadIdx.x;
        int n = idx >> 6, c = idx & 63;
        featT[((size_t)b * N_PTS + n0 + n) * 64 + c] = t[c][n];
    }
}

// ---------------------------------------------------------------------------
// MFMA MLP: 64 cols (2 centroids) per block, 4 waves, bf16 16x16x32 MFMA.
__global__ __launch_bounds__(256, 2) void mlp_kernel(
    const float* __restrict__ xyz, const float* __restrict__ feat,
    const float* __restrict__ featT, int useT,
    const float* __restrict__ newxyz, const int* __restrict__ nidx,
    const short* __restrict__ WaB, const float* __restrict__ ba,
    const short* __restrict__ WbB, const float* __restrict__ bb,
    const short* __restrict__ WsB, const float* __restrict__ bs,
    const short* __restrict__ WcB, const float* __restrict__ bc,
    const short* __restrict__ WdB, const float* __restrict__ bd,
    float* __restrict__ pooled)
{
    __shared__ short Xt[64][104];
    __shared__ short Ht[64][136];
    __shared__ short Tt[64][136];

    const int tid = threadIdx.x;
    const int w = tid >> 6, l = tid & 63, l16 = l & 15, kg = l >> 4;
    const int cen0 = blockIdx.x * 2;
    const int b = cen0 >> 10;
    const int ocw = 32 * w;

    {
        const int col = tid >> 2, part = tid & 3;
        const int ci = cen0 + (col >> 5);
        const int nn = nidx[ci * K_SMP + (col & 31)];
        float v[16];
        if (useT) {
            const f32x4* src = (const f32x4*)(featT + ((size_t)b * N_PTS + nn) * 64 + part * 16);
            f32x4 f0 = src[0], f1 = src[1], f2 = src[2], f3 = src[3];
            v[0]=f0[0]; v[1]=f0[1]; v[2]=f0[2]; v[3]=f0[3];
            v[4]=f1[0]; v[5]=f1[1]; v[6]=f1[2]; v[7]=f1[3];
            v[8]=f2[0]; v[9]=f2[1]; v[10]=f2[2]; v[11]=f2[3];
            v[12]=f3[0]; v[13]=f3[1]; v[14]=f3[2]; v[15]=f3[3];
        } else {
            const float* F = feat + (size_t)b * C_FEAT * N_PTS + nn;
#pragma unroll
            for (int q = 0; q < 16; ++q) v[q] = F[(size_t)(part * 16 + q) * N_PTS];
        }
        bf16x8 h0, h1;
#pragma unroll
        for (int q = 0; q < 8; ++q) { h0[q] = f2bf(v[q]); h1[q] = f2bf(v[q + 8]); }
        *(bf16x8*)&Xt[col][part * 16]     = h0;
        *(bf16x8*)&Xt[col][part * 16 + 8] = h1;
        if (part == 0) {
            bf16x8 hx, z;
#pragma unroll
            for (int q = 0; q < 8; ++q) { hx[q] = 0; z[q] = 0; }
            hx[0] = f2bf(xyz[((size_t)b * N_PTS + nn) * 3 + 0] - newxyz[ci * 3 + 0]);
            hx[1] = f2bf(xyz[((size_t)b * N_PTS + nn) * 3 + 1] - newxyz[ci * 3 + 1]);
            hx[2] = f2bf(xyz[((size_t)b * N_PTS + nn) * 3 + 2] - newxyz[ci * 3 + 2]);
            *(bf16x8*)&Xt[col][64] = hx;
            *(bf16x8*)&Xt[col][72] = z;
            *(bf16x8*)&Xt[col][80] = z;
            *(bf16x8*)&Xt[col][88] = z;
        }
    }
    __syncthreads();

    f32x4 accA[2][4], accS[2][4];
#pragma unroll
    for (int o = 0; o < 2; ++o)
#pragma unroll
        for (int ct = 0; ct < 4; ++ct) {
#pragma unroll
            for (int r = 0; r < 4; ++r) { accA[o][ct][r] = 0.f; accS[o][ct][r] = 0.f; }
        }
#pragma unroll
    for (int k = 0; k < 3; ++k) {
        bf16x8 xb[4];
#pragma unroll
        for (int ct = 0; ct < 4; ++ct)
            xb[ct] = *(const bf16x8*)&Xt[ct * 16 + l16][k * 32 + kg * 8];
#pragma unroll
        for (int o = 0; o < 2; ++o) {
            const int row = ocw + o * 16 + l16;
            bf16x8 wa  = *(const bf16x8*)(WaB + row * 96 + k * 32 + kg * 8);
            bf16x8 wsv = *(const bf16x8*)(WsB + row * 96 + k * 32 + kg * 8);
#pragma unroll
            for (int ct = 0; ct < 4; ++ct) {
                accA[o][ct] = __builtin_amdgcn_mfma_f32_16x16x32_bf16(wa,  xb[ct], accA[o][ct], 0, 0, 0);
                accS[o][ct] = __builtin_amdgcn_mfma_f32_16x16x32_bf16(wsv, xb[ct], accS[o][ct], 0, 0, 0);
            }
        }
    }
#pragma unroll
    for (int o = 0; o < 2; ++o) {
        const f32x4 bav = *(const f32x4*)(ba + ocw + o * 16 + kg * 4);
#pragma unroll
        for (int ct = 0; ct < 4; ++ct) {
            s16x4 hv;
#pragma unroll
            for (int r = 0; r < 4; ++r) hv[r] = f2bf(fmaxf(accA[o][ct][r] + bav[r], 0.f));
            *(s16x4*)&Ht[ct * 16 + l16][ocw + o * 16 + kg * 4] = hv;
        }
    }
    __syncthreads();

    f32x4 accB[2][4];
#pragma unroll
    for (int o = 0; o < 2; ++o)
#pragma unroll
        for (int ct = 0; ct < 4; ++ct) {
#pragma unroll
            for (int r = 0; r < 4; ++r) accB[o][ct][r] = 0.f;
        }
#pragma unroll
    for (int k = 0; k < 4; ++k) {
        bf16x8 xb[4];
#pragma unroll
        for (int ct = 0; ct < 4; ++ct)
            xb[ct] = *(const bf16x8*)&Ht[ct * 16 + l16][k * 32 + kg * 8];
#pragma unroll
        for (int o = 0; o < 2; ++o) {
            const int row = ocw + o * 16 + l16;
            bf16x8 wbv = *(const bf16x8*)(WbB + row * 128 + k * 32 + kg * 8);
#pragma unroll
            for (int ct = 0; ct < 4; ++ct)
                accB[o][ct] = __builtin_amdgcn_mfma_f32_16x16x32_bf16(wbv, xb[ct], accB[o][ct], 0, 0, 0);
        }
    }
    f32x4 hreg[2][4];
#pragma unroll
    for (int o = 0; o < 2; ++o) {
        const f32x4 bbv = *(const f32x4*)(bb + ocw + o * 16 + kg * 4);
        const f32x4 bsv = *(const f32x4*)(bs + ocw + o * 16 + kg * 4);
#pragma unroll
        for (int ct = 0; ct < 4; ++ct) {
#pragma unroll
            for (int r = 0; r < 4; ++r)
                hreg[o][ct][r] = fmaxf((accB[o][ct][r] + bbv[r]) + (accS[o][ct][r] + bsv[r]), 0.f);
        }
    }
    __syncthreads();
#pragma unroll
    for (int o = 0; o < 2; ++o)
#pragma unroll
        for (int ct = 0; ct < 4; ++ct) {
            s16x4 hv;
#pragma unroll
            for (int r = 0; r < 4; ++r) hv[r] = f2bf(hreg[o][ct][r]);
            *(s16x4*)&Ht[ct * 16 + l16][ocw + o * 16 + kg * 4] = hv;
        }
    __syncthreads();

    f32x4 accD[2][4];
#pragma unroll
    for (int o = 0; o < 2; ++o)
#pragma unroll
        for (int ct = 0; ct < 4; ++ct) {
#pragma unroll
            for (int r = 0; r < 4; ++r) accD[o][ct][r] = 0.f;
        }
    for (int cc = 0; cc < 4; ++cc) {
        f32x4 accC[2][4];
#pragma unroll
        for (int o = 0; o < 2; ++o)
#pragma unroll
            for (int ct = 0; ct < 4; ++ct) {
#pragma unroll
                for (int r = 0; r < 4; ++r) accC[o][ct][r] = 0.f;
            }
#pragma unroll
        for (int k = 0; k < 4; ++k) {
            bf16x8 xb[4];
#pragma unroll
            for (int ct = 0; ct < 4; ++ct)
                xb[ct] = *(const bf16x8*)&Ht[ct * 16 + l16][k * 32 + kg * 8];
#pragma unroll
            for (int o = 0; o < 2; ++o) {
                const int row = cc * 128 + ocw + o * 16 + l16;
                bf16x8 wcv = *(const bf16x8*)(WcB + row * 128 + k * 32 + kg * 8);
#pragma unroll
                for (int ct = 0; ct < 4; ++ct)
                    accC[o][ct] = __builtin_amdgcn_mfma_f32_16x16x32_bf16(wcv, xb[ct], accC[o][ct], 0, 0, 0);
            }
        }
        __syncthreads();
#pragma unroll
        for (int o = 0; o < 2; ++o) {
            const f32x4 bcv = *(const f32x4*)(bc + cc * 128 + ocw + o * 16 + kg * 4);
#pragma unroll
            for (int ct = 0; ct < 4; ++ct) {
                s16x4 tv;
#pragma unroll
                for (int r = 0; r < 4; ++r) tv[r] = f2bf(fmaxf(accC[o][ct][r] + bcv[r], 0.f));
                *(s16x4*)&Tt[ct * 16 + l16][ocw + o * 16 + kg * 4] = tv;
            }
        }
        __syncthreads();
#pragma unroll
        for (int k = 0; k < 4; ++k) {
            bf16x8 tb[4];
#pragma unroll
            for (int ct = 0; ct < 4; ++ct)
                tb[ct] = *(const bf16x8*)&Tt[ct * 16 + l16][k * 32 + kg * 8];
#pragma unroll
            for (int o = 0; o < 2; ++o) {
                const int row = ocw + o * 16 + l16;
                bf16x8 wdv = *(const bf16x8*)(WdB + row * 512 + cc * 128 + k * 32 + kg * 8);
#pragma unroll
                for (int ct = 0; ct < 4; ++ct)
                    accD[o][ct] = __builtin_amdgcn_mfma_f32_16x16x32_bf16(wdv, tb[ct], accD[o][ct], 0, 0, 0);
            }
        }
    }

    const int m0 = cen0 & 1023;
#pragma unroll
    for (int o = 0; o < 2; ++o) {
        const f32x4 bdv = *(const f32x4*)(bd + ocw + o * 16 + kg * 4);
#pragma unroll
        for (int r = 0; r < 4; ++r) {
            float a0 = fmaxf((accD[o][0][r] + bdv[r]) + hreg[o][0][r], 0.f);
            float a1 = fmaxf((accD[o][1][r] + bdv[r]) + hreg[o][1][r], 0.f);
            float a2 = fmaxf((accD[o][2][r] + bdv[r]) + hreg[o][2][r], 0.f);
            float a3 = fmaxf((accD[o][3][r] + bdv[r]) + hreg[o][3][r], 0.f);
            float u0 = fmaxf(a0, a1), u1 = fmaxf(a2, a3);
#pragma unroll
            for (int off = 1; off < 16; off <<= 1) {
                u0 = fmaxf(u0, __shfl_xor(u0, off));
                u1 = fmaxf(u1, __shfl_xor(u1, off));
            }
            if (l16 == 0) {
                const int oc = ocw + o * 16 + kg * 4 + r;
                pooled[((size_t)b * 128 + oc) * 1024 + m0]     = u0;
                pooled[((size_t)b * 128 + oc) * 1024 + m0 + 1] = u1;
            }
        }
    }
}

// ---------------------------------------------------------------------------
extern "C" void kernel_launch(void* const* d_in, const int* in_sizes, int n_in,
                              void* d_out, int out_size, void* d_ws, size_t ws_size,
                              hipStream_t stream)
{
    const float* xyz  = (const float*)d_in[0];
    const float* feat = (const float*)d_in[1];
    const float* Wa = (const float*)d_in[2];   const float* ba = (const float*)d_in[3];
    const float* Wb = (const float*)d_in[4];   const float* bb = (const float*)d_in[5];
    const float* Ws = (const float*)d_in[6];   const float* bs = (const float*)d_in[7];
    const float* Wc = (const float*)d_in[8];   const float* bc = (const float*)d_in[9];
    const float* Wd = (const float*)d_in[10];  const float* bd = (const float*)d_in[11];

    float* out    = (float*)d_out;
    float* newxyz = out;
    float* pooled = out + 4 * 1024 * 3;
    float* idxf   = pooled + 4 * 128 * 1024;

    char* ws = (char*)d_ws;
    float4* gsxyz = (float4*)ws;                 // 1 MiB; reused as nidx after fps
    int*    nidx  = (int*)ws;
    short* WaB = (short*)(ws + (1 << 20));       // 128*96
    short* WsB = WaB + 128 * 96;                 // 128*96
    short* WbB = WsB + 128 * 96;                 // 128*128
    short* WcB = WbB + 128 * 128;                // 512*128
    short* WdB = WcB + 512 * 128;                // 128*512
    int*   ghist = (int*)(WdB + 128 * 512);
    int*   gbase = ghist + 4 * NCELL;
    float* featT = (float*)(ws + (2 << 20));     // 16 MiB, optional

    const size_t need = (size_t)(2 << 20) + (size_t)4 * N_PTS * 64 * 4;
    const int useT = (ws_size >= need) ? 1 : 0;

    prep_w<<<(128 *  96 + 255) / 256, 256, 0, stream>>>(Wa, WaB, 128,  67,  96, 1);
    prep_w<<<(128 *  96 + 255) / 256, 256, 0, stream>>>(Ws, WsB, 128,  67,  96, 1);
    prep_w<<<(128 * 128 + 255) / 256, 256, 0, stream>>>(Wb, WbB, 128, 128, 128, 0);
    prep_w<<<(512 * 128 + 255) / 256, 256, 0, stream>>>(Wc, WcB, 512, 128, 128, 0);
    prep_w<<<(128 * 512 + 255) / 256, 256, 0, stream>>>(Wd, WdB, 128, 512, 512, 0);
    if (useT) tfeat_kernel<<<dim3(N_PTS / 64, 4), 256, 0, stream>>>(feat, featT);

    hist_kernel   <<<4, 1024,  0, stream>>>(xyz, ghist);
    scan_kernel   <<<4, NCELL, 0, stream>>>(ghist, gbase);
    scatter_kernel<<<4, 1024,  0, stream>>>(xyz, gbase, gsxyz);

    fps_kernel<<<4, 1024, 0, stream>>>(xyz, gsxyz, newxyz, idxf);
    ball_kernel<<<1024, 256, 0, stream>>>(xyz, newxyz, nidx);
    mlp_kernel<<<2048, 256, 0, stream>>>(xyz, feat, featT, useT, newxyz, nidx,
                                         WaB, ba, WbB, bb, WsB, bs,
                                         WcB, bc, WdB, bd, pooled);
}

// Round 7
// 2550.784 us; speedup vs baseline: 1.0011x; 1.0011x over previous
//
#include <hip/hip_runtime.h>

#define N_PTS   16384
#define M_CENT  1024
#define K_SMP   32
#define C_FEAT  64
#define NCELL   512

using bf16x8 = __attribute__((ext_vector_type(8))) short;
using s16x4  = __attribute__((ext_vector_type(4))) short;
using f32x4  = __attribute__((ext_vector_type(4))) float;

__device__ inline short f2bf(float f) {            // f32 -> bf16 RNE
    unsigned u = __float_as_uint(f);
    u += 0x7fffu + ((u >> 16) & 1u);
    return (short)(u >> 16);
}

// 64-bit xor shuffle from two 32-bit shuffles
__device__ inline unsigned long long shfl_xor_u64(unsigned long long v, int m) {
    int lo = (int)(unsigned int)v;
    int hi = (int)(unsigned int)(v >> 32);
    lo = __shfl_xor(lo, m);
    hi = __shfl_xor(hi, m);
    return ((unsigned long long)(unsigned int)hi << 32) | (unsigned int)lo;
}

// ---------------------------------------------------------------------------
// Hilbert cell id (8x8x8 = 512 cells). Consecutive Hilbert cells are always
// face-adjacent -> tight per-lane bboxes -> good FPS pruning. Order affects
// only speed, never correctness.
__device__ inline int hcell_of(float x, float y, float z) {
    int xi = (int)(x * 8.0f); xi = xi < 0 ? 0 : (xi > 7 ? 7 : xi);
    int yi = (int)(y * 8.0f); yi = yi < 0 ? 0 : (yi > 7 ? 7 : yi);
    int zi = (int)(z * 8.0f); zi = zi < 0 ? 0 : (zi > 7 ? 7 : zi);
    unsigned X[3] = {(unsigned)xi, (unsigned)yi, (unsigned)zi};
#pragma unroll
    for (unsigned Q = 4; Q > 1; Q >>= 1) {
        unsigned P = Q - 1;
#pragma unroll
        for (int i = 0; i < 3; ++i) {
            if (X[i] & Q) X[0] ^= P;
            else { unsigned t = (X[0] ^ X[i]) & P; X[0] ^= t; X[i] ^= t; }
        }
    }
    X[1] ^= X[0]; X[2] ^= X[1];
    unsigned t = 0;
#pragma unroll
    for (unsigned Q = 4; Q > 1; Q >>= 1)
        if (X[2] & Q) t ^= Q - 1;
    X[0] ^= t; X[1] ^= t; X[2] ^= t;
    int h = 0;
#pragma unroll
    for (int q = 2; q >= 0; --q)
        h = (h << 3) | (((X[0] >> q) & 1) << 2) | (((X[1] >> q) & 1) << 1) | ((X[2] >> q) & 1);
    return h;
}

// ---------------------------------------------------------------------------
__global__ __launch_bounds__(1024) void hist_kernel(
    const float* __restrict__ xyz, int* __restrict__ ghist)
{
    __shared__ int h[NCELL];
    const int b = blockIdx.x, tid = threadIdx.x;
    if (tid < NCELL) h[tid] = 0;
    __syncthreads();
    const float* P = xyz + (size_t)b * N_PTS * 3;
    for (int i = 0; i < 16; ++i) {
        const int p = tid + (i << 10);
        atomicAdd(&h[hcell_of(P[p*3], P[p*3+1], P[p*3+2])], 1);
    }
    __syncthreads();
    if (tid < NCELL) ghist[b * NCELL + tid] = h[tid];
}

__global__ __launch_bounds__(NCELL) void scan_kernel(
    const int* __restrict__ ghist, int* __restrict__ gbase)
{
    __shared__ int h[NCELL];
    const int b = blockIdx.x, t = threadIdx.x;
    h[t] = ghist[b * NCELL + t];
    __syncthreads();
    int s = 0;
    for (int i = 0; i < t; ++i) s += h[i];
    gbase[b * NCELL + t] = s;
}

__global__ __launch_bounds__(1024) void scatter_kernel(
    const float* __restrict__ xyz, int* __restrict__ gbase,
    float4* __restrict__ gsxyz)
{
    const int b = blockIdx.x, tid = threadIdx.x;
    const float* P = xyz + (size_t)b * N_PTS * 3;
    for (int i = 0; i < 16; ++i) {
        const int p = tid + (i << 10);
        float x = P[p*3], y = P[p*3+1], z = P[p*3+2];
        int c = hcell_of(x, y, z);
        int pos = atomicAdd(&gbase[b * NCELL + c], 1);
        gsxyz[(size_t)b * N_PTS + pos] = make_float4(x, y, z, __int_as_float(p));
    }
}

// ---------------------------------------------------------------------------
// FPS, bit-exact pruned.
// Register-residency enforcement (r7): the ~100-reg live set (px/py/pz/mind/
// klo + bbox + coord cache) was being spilled because the RA targeted 8
// waves/EU (64 VGPR). Two redundant mechanisms force a 4-waves/EU target
// (128-VGPR budget):
//   (1) amdgpu_waves_per_eu(4,4) pins the occupancy target;
//   (2) 82 KB of LDS (kept alive behind an unprovable guard) caps achievable
//       occupancy at 1 block/CU = 4 waves/EU in the RA's own model.
// Runtime cost of (2) is zero: grid = 4 blocks on 256 CUs.
__global__ __launch_bounds__(1024)
__attribute__((amdgpu_waves_per_eu(4, 4)))
void fps_kernel(
    const float* __restrict__ xyz,
    const float4* __restrict__ gsxyz,
    float* __restrict__ newxyz_out,
    float* __restrict__ idxf_out)
{
#pragma clang fp contract(off)
    const int b = blockIdx.x, tid = threadIdx.x;
    const int wid = tid >> 6, lane = tid & 63;
    const float4* S = gsxyz + (size_t)b * N_PTS;

    __shared__ unsigned long long wkeys[2][16];   // parity double-buffer
    __shared__ float4 wcoord[2][16];
    __shared__ char occ_pad[83968];               // occupancy clamp, see header
    if (idxf_out == nullptr) {                    // never true at runtime;
        occ_pad[tid] = (char)tid;                 // unprovable at compile time
        __syncthreads();
        newxyz_out[tid] = (float)occ_pad[tid ^ 1];
    }

    float px[16], py[16], pz[16], mind[16];
    unsigned klo[16];
    float lox = 1e30f, hix = -1e30f, loy = 1e30f, hiy = -1e30f, loz = 1e30f, hiz = -1e30f;
#pragma unroll
    for (int i = 0; i < 16; ++i) {
        const float4 v = S[tid * 16 + i];
        px[i] = v.x; py[i] = v.y; pz[i] = v.z;
        const int orig = __float_as_int(v.w);
        klo[i] = ((unsigned)(16383 - orig) << 16) | (unsigned)(tid * 16 + i);
        mind[i] = __int_as_float(0x7f800000);
        lox = fminf(lox, v.x); hix = fmaxf(hix, v.x);
        loy = fminf(loy, v.y); hiy = fmaxf(hiy, v.y);
        loz = fminf(loz, v.z); hiz = fmaxf(hiz, v.z);
    }

    const float* P = xyz + (size_t)b * N_PTS * 3;
    float cx = P[0], cy = P[1], cz = P[2];
    if (tid == 0) {
        idxf_out[b * M_CENT] = 0.0f;
        newxyz_out[(b * M_CENT) * 3 + 0] = cx;
        newxyz_out[(b * M_CENT) * 3 + 1] = cy;
        newxyz_out[(b * M_CENT) * 3 + 2] = cz;
    }
    __syncthreads();

    unsigned long long bkey = 0x7f80000000000000ull;   // lane max-mind = +inf
    unsigned long long wkey = 0x7f80000000000000ull;   // wave max-mind = +inf
    float cwx = 0.f, cwy = 0.f, cwz = 0.f;             // owner-lane coord cache

    for (int j = 1; j < M_CENT; ++j) {
        const int par = j & 1;
        // lane-level conservative reject (bit-exact: fminf(mind,d)==mind
        // whenever d>=mind; margin 1.5e-5 >> worst-case f32 rounding)
        float tx = fmaxf(fmaxf(lox - cx, cx - hix), 0.0f);
        float ty = fmaxf(fmaxf(loy - cy, cy - hiy), 0.0f);
        float tz = fmaxf(fmaxf(loz - cz, cz - hiz), 0.0f);
        float lb = (tx * tx + ty * ty) + tz * tz;
        float lmax = __uint_as_float((unsigned)(bkey >> 32));
        bool need = (lb * 0.999985f) < lmax;

        if (__any(need)) {
            // pass 1: distances + value-only max
            float bv = -1.0f;
#pragma unroll
            for (int i = 0; i < 16; ++i) {
                float dx = px[i] - cx;
                float dy = py[i] - cy;
                float dz = pz[i] - cz;
                float xx = dx * dx, yy = dy * dy, zz = dz * dz;
                float d  = (xx + yy) + zz;            // numpy order, no fma
                float mn = fminf(mind[i], d);
                mind[i] = mn;
                bv = fmaxf(bv, mn);
            }
            // pass 2: tie-break (max klo = smallest original idx) + coords
            unsigned bk = 0u;
            float wxx = 0.f, wyy = 0.f, wzz = 0.f;
#pragma unroll
            for (int i = 0; i < 16; ++i) {
                bool c = (mind[i] == bv) && (klo[i] >= bk);
                bk  = c ? klo[i] : bk;
                wxx = c ? px[i]  : wxx;
                wyy = c ? py[i]  : wyy;
                wzz = c ? pz[i]  : wzz;
            }
            bkey = ((unsigned long long)__float_as_uint(bv) << 32) | bk;
            cwx = wxx; cwy = wyy; cwz = wzz;

            unsigned long long w = bkey;
#pragma unroll
            for (int off = 32; off >= 1; off >>= 1) {
                unsigned long long o = shfl_xor_u64(w, off);
                if (o > w) w = o;
            }
            wkey = w;
        }
        // unique owner lane (keys are unique) publishes key + coords
        if (bkey == wkey) {
            wkeys[par][wid]  = wkey;
            wcoord[par][wid] = make_float4(cwx, cwy, cwz, 0.f);
        }
        __syncthreads();

        unsigned long long k2 = wkeys[par][lane & 15];
#pragma unroll
        for (int off = 8; off >= 1; off >>= 1) {
            unsigned long long o = shfl_xor_u64(k2, off);
            if (o > k2) k2 = o;
        }
        const unsigned int kl = (unsigned int)k2;
        const int winw = (int)((kl & 0xFFFFu) >> 10);
        const float4 wc = wcoord[par][winw];          // broadcast LDS read
        cx = wc.x; cy = wc.y; cz = wc.z;
        if (tid == 0) {
            const int orig = 16383 - (int)(kl >> 16);
            idxf_out[b * M_CENT + j] = (float)orig;
            newxyz_out[(b * M_CENT + j) * 3 + 0] = cx;
            newxyz_out[(b * M_CENT + j) * 3 + 1] = cy;
            newxyz_out[(b * M_CENT + j) * 3 + 2] = cz;
        }
        // no second barrier: parity alternates, and reaching the same parity
        // again requires passing the next barrier, which happens-after all
        // reads above.
    }
}

// ---------------------------------------------------------------------------
__global__ __launch_bounds__(256) void ball_kernel(
    const float* __restrict__ xyz,
    const float* __restrict__ newxyz,
    int* __restrict__ nidx)
{
#pragma clang fp contract(off)
    const float R2 = (float)(0.1 * 0.1);
    const int gw   = blockIdx.x * 4 + (threadIdx.x >> 6);
    const int lane = threadIdx.x & 63;
    const int b    = gw >> 10;
    const float* P = xyz + (size_t)b * N_PTS * 3;
    const float cx = newxyz[gw * 3 + 0];
    const float cy = newxyz[gw * 3 + 1];
    const float cz = newxyz[gw * 3 + 2];
    int* out = nidx + gw * K_SMP;

    int cnt = 0, first = -1;
    for (int base = 0; base < N_PTS; base += 64) {
        const int n = base + lane;
        float dx = P[n * 3 + 0] - cx;
        float dy = P[n * 3 + 1] - cy;
        float dz = P[n * 3 + 2] - cz;
        float xx = dx * dx, yy = dy * dy, zz = dz * dz;
        float d2 = (xx + yy) + zz;
        bool inb = d2 < R2;
        unsigned long long mask = __ballot(inb);
        if (mask) {
            if (first < 0) first = base + __ffsll(mask) - 1;
            int before = __popcll(mask & ((1ull << lane) - 1ull));
            int slot = cnt + before;
            if (inb && slot < K_SMP) out[slot] = n;
            cnt += __popcll(mask);
            if (cnt >= K_SMP) break;
        }
    }
    for (int s = cnt + lane; s < K_SMP; s += 64) out[s] = first;
}

// ---------------------------------------------------------------------------
// Weight prep: f32 (OC,IC) -> bf16 (OC,ICP). remap=1 reorders input channels
// from [xyz(3), feat(64)] to [feat(64), xyz(3), pad] to match Xt layout.
__global__ void prep_w(const float* __restrict__ src, short* __restrict__ dst,
                       int OC, int IC, int ICP, int remap)
{
    int i = blockIdx.x * 256 + threadIdx.x;
    if (i >= OC * ICP) return;
    int oc = i / ICP, ic = i - oc * ICP;
    float v = 0.0f;
    if (remap) {
        if (ic < 64)      v = src[oc * IC + 3 + ic];
        else if (ic < 67) v = src[oc * IC + (ic - 64)];
    } else if (ic < IC)   v = src[oc * IC + ic];
    dst[i] = f2bf(v);
}

// feat (B,64,N) -> featT (B,N,64)
__global__ __launch_bounds__(256) void tfeat_kernel(
    const float* __restrict__ feat, float* __restrict__ featT)
{
    __shared__ float t[64][65];
    const int b = blockIdx.y;
    const int n0 = blockIdx.x * 64;
    for (int it = 0; it < 16; ++it) {
        int idx = it * 256 + threadIdx.x;
        int c = idx >> 6, n = idx & 63;
        t[c][n] = feat[((size_t)b * 64 + c) * N_PTS + n0 + n];
    }
    __syncthreads();
    for (int it = 0; it < 16; ++it) {
        int idx = it * 256 + threadIdx.x;
        int n = idx >> 6, c = idx & 63;
        featT[((size_t)b * N_PTS + n0 + n) * 64 + c] = t[c][n];
    }
}

// ---------------------------------------------------------------------------
// MFMA MLP: 64 cols (2 centroids) per block, 4 waves, bf16 16x16x32 MFMA.
__global__ __launch_bounds__(256, 2) void mlp_kernel(
    const float* __restrict__ xyz, const float* __restrict__ feat,
    const float* __restrict__ featT, int useT,
    const float* __restrict__ newxyz, const int* __restrict__ nidx,
    const short* __restrict__ WaB, const float* __restrict__ ba,
    const short* __restrict__ WbB, const float* __restrict__ bb,
    const short* __restrict__ WsB, const float* __restrict__ bs,
    const short* __restrict__ WcB, const float* __restrict__ bc,
    const short* __restrict__ WdB, const float* __restrict__ bd,
    float* __restrict__ pooled)
{
    __shared__ short Xt[64][104];
    __shared__ short Ht[64][136];
    __shared__ short Tt[64][136];

    const int tid = threadIdx.x;
    const int w = tid >> 6, l = tid & 63, l16 = l & 15, kg = l >> 4;
    const int cen0 = blockIdx.x * 2;
    const int b = cen0 >> 10;
    const int ocw = 32 * w;

    {
        const int col = tid >> 2, part = tid & 3;
        const int ci = cen0 + (col >> 5);
        const int nn = nidx[ci * K_SMP + (col & 31)];
        float v[16];
        if (useT) {
            const f32x4* src = (const f32x4*)(featT + ((size_t)b * N_PTS + nn) * 64 + part * 16);
            f32x4 f0 = src[0], f1 = src[1], f2 = src[2], f3 = src[3];
            v[0]=f0[0]; v[1]=f0[1]; v[2]=f0[2]; v[3]=f0[3];
            v[4]=f1[0]; v[5]=f1[1]; v[6]=f1[2]; v[7]=f1[3];
            v[8]=f2[0]; v[9]=f2[1]; v[10]=f2[2]; v[11]=f2[3];
            v[12]=f3[0]; v[13]=f3[1]; v[14]=f3[2]; v[15]=f3[3];
        } else {
            const float* F = feat + (size_t)b * C_FEAT * N_PTS + nn;
#pragma unroll
            for (int q = 0; q < 16; ++q) v[q] = F[(size_t)(part * 16 + q) * N_PTS];
        }
        bf16x8 h0, h1;
#pragma unroll
        for (int q = 0; q < 8; ++q) { h0[q] = f2bf(v[q]); h1[q] = f2bf(v[q + 8]); }
        *(bf16x8*)&Xt[col][part * 16]     = h0;
        *(bf16x8*)&Xt[col][part * 16 + 8] = h1;
        if (part == 0) {
            bf16x8 hx, z;
#pragma unroll
            for (int q = 0; q < 8; ++q) { hx[q] = 0; z[q] = 0; }
            hx[0] = f2bf(xyz[((size_t)b * N_PTS + nn) * 3 + 0] - newxyz[ci * 3 + 0]);
            hx[1] = f2bf(xyz[((size_t)b * N_PTS + nn) * 3 + 1] - newxyz[ci * 3 + 1]);
            hx[2] = f2bf(xyz[((size_t)b * N_PTS + nn) * 3 + 2] - newxyz[ci * 3 + 2]);
            *(bf16x8*)&Xt[col][64] = hx;
            *(bf16x8*)&Xt[col][72] = z;
            *(bf16x8*)&Xt[col][80] = z;
            *(bf16x8*)&Xt[col][88] = z;
        }
    }
    __syncthreads();

    f32x4 accA[2][4], accS[2][4];
#pragma unroll
    for (int o = 0; o < 2; ++o)
#pragma unroll
        for (int ct = 0; ct < 4; ++ct) {
#pragma unroll
            for (int r = 0; r < 4; ++r) { accA[o][ct][r] = 0.f; accS[o][ct][r] = 0.f; }
        }
#pragma unroll
    for (int k = 0; k < 3; ++k) {
        bf16x8 xb[4];
#pragma unroll
        for (int ct = 0; ct < 4; ++ct)
            xb[ct] = *(const bf16x8*)&Xt[ct * 16 + l16][k * 32 + kg * 8];
#pragma unroll
        for (int o = 0; o < 2; ++o) {
            const int row = ocw + o * 16 + l16;
            bf16x8 wa  = *(const bf16x8*)(WaB + row * 96 + k * 32 + kg * 8);
            bf16x8 wsv = *(const bf16x8*)(WsB + row * 96 + k * 32 + kg * 8);
#pragma unroll
            for (int ct = 0; ct < 4; ++ct) {
                accA[o][ct] = __builtin_amdgcn_mfma_f32_16x16x32_bf16(wa,  xb[ct], accA[o][ct], 0, 0, 0);
                accS[o][ct] = __builtin_amdgcn_mfma_f32_16x16x32_bf16(wsv, xb[ct], accS[o][ct], 0, 0, 0);
            }
        }
    }
#pragma unroll
    for (int o = 0; o < 2; ++o) {
        const f32x4 bav = *(const f32x4*)(ba + ocw + o * 16 + kg * 4);
#pragma unroll
        for (int ct = 0; ct < 4; ++ct) {
            s16x4 hv;
#pragma unroll
            for (int r = 0; r < 4; ++r) hv[r] = f2bf(fmaxf(accA[o][ct][r] + bav[r], 0.f));
            *(s16x4*)&Ht[ct * 16 + l16][ocw + o * 16 + kg * 4] = hv;
        }
    }
    __syncthreads();

    f32x4 accB[2][4];
#pragma unroll
    for (int o = 0; o < 2; ++o)
#pragma unroll
        for (int ct = 0; ct < 4; ++ct) {
#pragma unroll
            for (int r = 0; r < 4; ++r) accB[o][ct][r] = 0.f;
        }
#pragma unroll
    for (int k = 0; k < 4; ++k) {
        bf16x8 xb[4];
#pragma unroll
        for (int ct = 0; ct < 4; ++ct)
            xb[ct] = *(const bf16x8*)&Ht[ct * 16 + l16][k * 32 + kg * 8];
#pragma unroll
        for (int o = 0; o < 2; ++o) {
            const int row = ocw + o * 16 + l16;
            bf16x8 wbv = *(const bf16x8*)(WbB + row * 128 + k * 32 + kg * 8);
#pragma unroll
            for (int ct = 0; ct < 4; ++ct)
                accB[o][ct] = __builtin_amdgcn_mfma_f32_16x16x32_bf16(wbv, xb[ct], accB[o][ct], 0, 0, 0);
        }
    }
    f32x4 hreg[2][4];
#pragma unroll
    for (int o = 0; o < 2; ++o) {
        const f32x4 bbv = *(const f32x4*)(bb + ocw + o * 16 + kg * 4);
        const f32x4 bsv = *(const f32x4*)(bs + ocw + o * 16 + kg * 4);
#pragma unroll
        for (int ct = 0; ct < 4; ++ct) {
#pragma unroll
            for (int r = 0; r < 4; ++r)
                hreg[o][ct][r] = fmaxf((accB[o][ct][r] + bbv[r]) + (accS[o][ct][r] + bsv[r]), 0.f);
        }
    }
    __syncthreads();
#pragma unroll
    for (int o = 0; o < 2; ++o)
#pragma unroll
        for (int ct = 0; ct < 4; ++ct) {
            s16x4 hv;
#pragma unroll
            for (int r = 0; r < 4; ++r) hv[r] = f2bf(hreg[o][ct][r]);
            *(s16x4*)&Ht[ct * 16 + l16][ocw + o * 16 + kg * 4] = hv;
        }
    __syncthreads();

    f32x4 accD[2][4];
#pragma unroll
    for (int o = 0; o < 2; ++o)
#pragma unroll
        for (int ct = 0; ct < 4; ++ct) {
#pragma unroll
            for (int r = 0; r < 4; ++r) accD[o][ct][r] = 0.f;
        }
    for (int cc = 0; cc < 4; ++cc) {
        f32x4 accC[2][4];
#pragma unroll
        for (int o = 0; o < 2; ++o)
#pragma unroll
            for (int ct = 0; ct < 4; ++ct) {
#pragma unroll
                for (int r = 0; r < 4; ++r) accC[o][ct][r] = 0.f;
            }
#pragma unroll
        for (int k = 0; k < 4; ++k) {
            bf16x8 xb[4];
#pragma unroll
            for (int ct = 0; ct < 4; ++ct)
                xb[ct] = *(const bf16x8*)&Ht[ct * 16 + l16][k * 32 + kg * 8];
#pragma unroll
            for (int o = 0; o < 2; ++o) {
                const int row = cc * 128 + ocw + o * 16 + l16;
                bf16x8 wcv = *(const bf16x8*)(WcB + row * 128 + k * 32 + kg * 8);
#pragma unroll
                for (int ct = 0; ct < 4; ++ct)
                    accC[o][ct] = __builtin_amdgcn_mfma_f32_16x16x32_bf16(wcv, xb[ct], accC[o][ct], 0, 0, 0);
            }
        }
        __syncthreads();
#pragma unroll
        for (int o = 0; o < 2; ++o) {
            const f32x4 bcv = *(const f32x4*)(bc + cc * 128 + ocw + o * 16 + kg * 4);
#pragma unroll
            for (int ct = 0; ct < 4; ++ct) {
                s16x4 tv;
#pragma unroll
                for (int r = 0; r < 4; ++r) tv[r] = f2bf(fmaxf(accC[o][ct][r] + bcv[r], 0.f));
                *(s16x4*)&Tt[ct * 16 + l16][ocw + o * 16 + kg * 4] = tv;
            }
        }
        __syncthreads();
#pragma unroll
        for (int k = 0; k < 4; ++k) {
            bf16x8 tb[4];
#pragma unroll
            for (int ct = 0; ct < 4; ++ct)
                tb[ct] = *(const bf16x8*)&Tt[ct * 16 + l16][k * 32 + kg * 8];
#pragma unroll
            for (int o = 0; o < 2; ++o) {
                const int row = ocw + o * 16 + l16;
                bf16x8 wdv = *(const bf16x8*)(WdB + row * 512 + cc * 128 + k * 32 + kg * 8);
#pragma unroll
                for (int ct = 0; ct < 4; ++ct)
                    accD[o][ct] = __builtin_amdgcn_mfma_f32_16x16x32_bf16(wdv, tb[ct], accD[o][ct], 0, 0, 0);
            }
        }
    }

    const int m0 = cen0 & 1023;
#pragma unroll
    for (int o = 0; o < 2; ++o) {
        const f32x4 bdv = *(const f32x4*)(bd + ocw + o * 16 + kg * 4);
#pragma unroll
        for (int r = 0; r < 4; ++r) {
            float a0 = fmaxf((accD[o][0][r] + bdv[r]) + hreg[o][0][r], 0.f);
            float a1 = fmaxf((accD[o][1][r] + bdv[r]) + hreg[o][1][r], 0.f);
            float a2 = fmaxf((accD[o][2][r] + bdv[r]) + hreg[o][2][r], 0.f);
            float a3 = fmaxf((accD[o][3][r] + bdv[r]) + hreg[o][3][r], 0.f);
            float u0 = fmaxf(a0, a1), u1 = fmaxf(a2, a3);
#pragma unroll
            for (int off = 1; off < 16; off <<= 1) {
                u0 = fmaxf(u0, __shfl_xor(u0, off));
                u1 = fmaxf(u1, __shfl_xor(u1, off));
            }
            if (l16 == 0) {
                const int oc = ocw + o * 16 + kg * 4 + r;
                pooled[((size_t)b * 128 + oc) * 1024 + m0]     = u0;
                pooled[((size_t)b * 128 + oc) * 1024 + m0 + 1] = u1;
            }
        }
    }
}

// ---------------------------------------------------------------------------
extern "C" void kernel_launch(void* const* d_in, const int* in_sizes, int n_in,
                              void* d_out, int out_size, void* d_ws, size_t ws_size,
                              hipStream_t stream)
{
    const float* xyz  = (const float*)d_in[0];
    const float* feat = (const float*)d_in[1];
    const float* Wa = (const float*)d_in[2];   const float* ba = (const float*)d_in[3];
    const float* Wb = (const float*)d_in[4];   const float* bb = (const float*)d_in[5];
    const float* Ws = (const float*)d_in[6];   const float* bs = (const float*)d_in[7];
    const float* Wc = (const float*)d_in[8];   const float* bc = (const float*)d_in[9];
    const float* Wd = (const float*)d_in[10];  const float* bd = (const float*)d_in[11];

    float* out    = (float*)d_out;
    float* newxyz = out;
    float* pooled = out + 4 * 1024 * 3;
    float* idxf   = pooled + 4 * 128 * 1024;

    char* ws = (char*)d_ws;
    float4* gsxyz = (float4*)ws;                 // 1 MiB; reused as nidx after fps
    int*    nidx  = (int*)ws;
    short* WaB = (short*)(ws + (1 << 20));       // 128*96
    short* WsB = WaB + 128 * 96;                 // 128*96
    short* WbB = WsB + 128 * 96;                 // 128*128
    short* WcB = WbB + 128 * 128;                // 512*128
    short* WdB = WcB + 512 * 128;                // 128*512
    int*   ghist = (int*)(WdB + 128 * 512);
    int*   gbase = ghist + 4 * NCELL;
    float* featT = (float*)(ws + (2 << 20));     // 16 MiB, optional

    const size_t need = (size_t)(2 << 20) + (size_t)4 * N_PTS * 64 * 4;
    const int useT = (ws_size >= need) ? 1 : 0;

    prep_w<<<(128 *  96 + 255) / 256, 256, 0, stream>>>(Wa, WaB, 128,  67,  96, 1);
    prep_w<<<(128 *  96 + 255) / 256, 256, 0, stream>>>(Ws, WsB, 128,  67,  96, 1);
    prep_w<<<(128 * 128 + 255) / 256, 256, 0, stream>>>(Wb, WbB, 128, 128, 128, 0);
    prep_w<<<(512 * 128 + 255) / 256, 256, 0, stream>>>(Wc, WcB, 512, 128, 128, 0);
    prep_w<<<(128 * 512 + 255) / 256, 256, 0, stream>>>(Wd, WdB, 128, 512, 512, 0);
    if (useT) tfeat_kernel<<<dim3(N_PTS / 64, 4), 256, 0, stream>>>(feat, featT);

    hist_kernel   <<<4, 1024,  0, stream>>>(xyz, ghist);
    scan_kernel   <<<4, NCELL, 0, stream>>>(ghist, gbase);
    scatter_kernel<<<4, 1024,  0, stream>>>(xyz, gbase, gsxyz);

    fps_kernel<<<4, 1024, 0, stream>>>(xyz, gsxyz, newxyz, idxf);
    ball_kernel<<<1024, 256, 0, stream>>>(xyz, newxyz, nidx);
    mlp_kernel<<<2048, 256, 0, stream>>>(xyz, feat, featT, useT, newxyz, nidx,
                                         WaB, ba, WbB, bb, WsB, bs,
                                         WcB, bc, WdB, bd, pooled);
}

// Round 8
// 2092.606 us; speedup vs baseline: 1.2203x; 1.2190x over previous
//
#include <hip/hip_runtime.h>

#define N_PTS   16384
#define M_CENT  1024
#define K_SMP   32
#define C_FEAT  64
#define NCELL   512

using bf16x8 = __attribute__((ext_vector_type(8))) short;
using s16x4  = __attribute__((ext_vector_type(4))) short;
using f32x4  = __attribute__((ext_vector_type(4))) float;

__device__ inline short f2bf(float f) {            // f32 -> bf16 RNE
    unsigned u = __float_as_uint(f);
    u += 0x7fffu + ((u >> 16) & 1u);
    return (short)(u >> 16);
}

// 64-bit xor shuffle from two 32-bit shuffles
__device__ inline unsigned long long shfl_xor_u64(unsigned long long v, int m) {
    int lo = (int)(unsigned int)v;
    int hi = (int)(unsigned int)(v >> 32);
    lo = __shfl_xor(lo, m);
    hi = __shfl_xor(hi, m);
    return ((unsigned long long)(unsigned int)hi << 32) | (unsigned int)lo;
}

// ---------------------------------------------------------------------------
// Hilbert cell id (8x8x8 = 512 cells). Consecutive Hilbert cells are always
// face-adjacent -> tight per-lane bboxes -> good FPS pruning. Order affects
// only speed, never correctness.
__device__ inline int hcell_of(float x, float y, float z) {
    int xi = (int)(x * 8.0f); xi = xi < 0 ? 0 : (xi > 7 ? 7 : xi);
    int yi = (int)(y * 8.0f); yi = yi < 0 ? 0 : (yi > 7 ? 7 : yi);
    int zi = (int)(z * 8.0f); zi = zi < 0 ? 0 : (zi > 7 ? 7 : zi);
    unsigned X[3] = {(unsigned)xi, (unsigned)yi, (unsigned)zi};
#pragma unroll
    for (unsigned Q = 4; Q > 1; Q >>= 1) {
        unsigned P = Q - 1;
#pragma unroll
        for (int i = 0; i < 3; ++i) {
            if (X[i] & Q) X[0] ^= P;
            else { unsigned t = (X[0] ^ X[i]) & P; X[0] ^= t; X[i] ^= t; }
        }
    }
    X[1] ^= X[0]; X[2] ^= X[1];
    unsigned t = 0;
#pragma unroll
    for (unsigned Q = 4; Q > 1; Q >>= 1)
        if (X[2] & Q) t ^= Q - 1;
    X[0] ^= t; X[1] ^= t; X[2] ^= t;
    int h = 0;
#pragma unroll
    for (int q = 2; q >= 0; --q)
        h = (h << 3) | (((X[0] >> q) & 1) << 2) | (((X[1] >> q) & 1) << 1) | ((X[2] >> q) & 1);
    return h;
}

// ---------------------------------------------------------------------------
__global__ __launch_bounds__(1024) void hist_kernel(
    const float* __restrict__ xyz, int* __restrict__ ghist)
{
    __shared__ int h[NCELL];
    const int b = blockIdx.x, tid = threadIdx.x;
    if (tid < NCELL) h[tid] = 0;
    __syncthreads();
    const float* P = xyz + (size_t)b * N_PTS * 3;
    for (int i = 0; i < 16; ++i) {
        const int p = tid + (i << 10);
        atomicAdd(&h[hcell_of(P[p*3], P[p*3+1], P[p*3+2])], 1);
    }
    __syncthreads();
    if (tid < NCELL) ghist[b * NCELL + tid] = h[tid];
}

__global__ __launch_bounds__(NCELL) void scan_kernel(
    const int* __restrict__ ghist, int* __restrict__ gbase)
{
    __shared__ int h[NCELL];
    const int b = blockIdx.x, t = threadIdx.x;
    h[t] = ghist[b * NCELL + t];
    __syncthreads();
    int s = 0;
    for (int i = 0; i < t; ++i) s += h[i];
    gbase[b * NCELL + t] = s;
}

__global__ __launch_bounds__(1024) void scatter_kernel(
    const float* __restrict__ xyz, int* __restrict__ gbase,
    float4* __restrict__ gsxyz)
{
    const int b = blockIdx.x, tid = threadIdx.x;
    const float* P = xyz + (size_t)b * N_PTS * 3;
    for (int i = 0; i < 16; ++i) {
        const int p = tid + (i << 10);
        float x = P[p*3], y = P[p*3+1], z = P[p*3+2];
        int c = hcell_of(x, y, z);
        int pos = atomicAdd(&gbase[b * NCELL + c], 1);
        gsxyz[(size_t)b * N_PTS + pos] = make_float4(x, y, z, __int_as_float(p));
    }
}

// ---------------------------------------------------------------------------
// FPS, bit-exact pruned. r8 redesign: the register live set is cut below the
// 64-VGPR allocation the RA insists on (r5-r7 PMC: VGPR_Count pinned at 64,
// WRITE_SIZE 368KB of scratch traffic). State split:
//   LDS : xs[16][1024] f32 (point x), minds[16][1024] f32 — conflict-free
//         [i][tid] layout (consecutive lanes -> consecutive banks).
//   VGPR: y[16], z[16], norig packed 2/reg (8), bbox (6), scalars  ~53.
// Cross-wave reduce: single-buffered wkeys/wcoord slots + TWO barriers per
// iteration. Skipped waves leave their slots untouched — valid, since the
// bbox bound proves none of their minds changed (so their max-key and argmax
// point are unchanged). Tie-break still max-norig = smallest original index
// (numpy argmax first-wins), so idx output is bit-exact.
__global__ __launch_bounds__(1024) void fps_kernel(
    const float* __restrict__ xyz,
    const float4* __restrict__ gsxyz,
    float* __restrict__ newxyz_out,
    float* __restrict__ idxf_out)
{
#pragma clang fp contract(off)
    const int b = blockIdx.x, tid = threadIdx.x;
    const int wid = tid >> 6, lane = tid & 63;
    const float4* S = gsxyz + (size_t)b * N_PTS;

    __shared__ float xs[16 * 1024];       // 64 KB
    __shared__ float minds[16 * 1024];    // 64 KB
    __shared__ unsigned long long wkeys[16];
    __shared__ float4 wcoord[16];

    float y[16], z[16];
    unsigned npk[8];                      // norig (=16383-orig), 2 per reg
    float lox = 1e30f, hix = -1e30f, loy = 1e30f, hiy = -1e30f, loz = 1e30f, hiz = -1e30f;
#pragma unroll
    for (int i = 0; i < 16; ++i) {
        const float4 v = S[tid * 16 + i];
        xs[i * 1024 + tid]    = v.x;
        minds[i * 1024 + tid] = __int_as_float(0x7f800000);   // +inf
        y[i] = v.y; z[i] = v.z;
        const unsigned norig = 16383u - (unsigned)__float_as_int(v.w);
        if (i & 1) npk[i >> 1] |= norig << 16;
        else       npk[i >> 1]  = norig;
        lox = fminf(lox, v.x); hix = fmaxf(hix, v.x);
        loy = fminf(loy, v.y); hiy = fmaxf(hiy, v.y);
        loz = fminf(loz, v.z); hiz = fmaxf(hiz, v.z);
    }
    if (tid < 16) wkeys[tid] = 0ull;

    const float* P = xyz + (size_t)b * N_PTS * 3;
    float cx = P[0], cy = P[1], cz = P[2];
    if (tid == 0) {
        idxf_out[b * M_CENT] = 0.0f;
        newxyz_out[(b * M_CENT) * 3 + 0] = cx;
        newxyz_out[(b * M_CENT) * 3 + 1] = cy;
        newxyz_out[(b * M_CENT) * 3 + 2] = cz;
    }
    __syncthreads();

    unsigned long long bkey = 0x7f80000000000000ull;   // lane max-mind = +inf

    for (int j = 1; j < M_CENT; ++j) {
        // lane-level conservative reject (bit-exact: fminf(mind,d)==mind
        // whenever d>=mind; margin 1.5e-5 >> worst-case f32 rounding)
        float tx = fmaxf(fmaxf(lox - cx, cx - hix), 0.0f);
        float ty = fmaxf(fmaxf(loy - cy, cy - hiy), 0.0f);
        float tz = fmaxf(fmaxf(loz - cz, cz - hiz), 0.0f);
        float lb = (tx * tx + ty * ty) + tz * tz;
        float lmax = __uint_as_float((unsigned)(bkey >> 32));
        bool need = (lb * 0.999985f) < lmax;

        if (__any(need)) {
            // pass 1: exact distances, fmin update, value-only max
            float bv = -1.0f;
#pragma unroll
            for (int i = 0; i < 16; ++i) {
                float xx = xs[i * 1024 + tid];
                float mo = minds[i * 1024 + tid];
                float dx = xx - cx;
                float dy = y[i] - cy;
                float dz = z[i] - cz;
                float xx2 = dx * dx, yy2 = dy * dy, zz2 = dz * dz;
                float d  = (xx2 + yy2) + zz2;          // numpy order, no fma
                float mn = fminf(mo, d);
                minds[i * 1024 + tid] = mn;
                bv = fmaxf(bv, mn);
            }
            // pass 2: tie-break (max norig = smallest orig) + y/z capture
            unsigned bk = 0u;
            float wy = 0.f, wz = 0.f;
#pragma unroll
            for (int i = 0; i < 16; ++i) {
                float mo = minds[i * 1024 + tid];
                unsigned nr = (i & 1) ? (npk[i >> 1] >> 16) : (npk[i >> 1] & 0xFFFFu);
                unsigned nk = (nr << 5) | (unsigned)(i + 1);
                bool c = (mo == bv) && (nk > bk);
                bk = c ? nk : bk;
                wy = c ? y[i] : wy;
                wz = c ? z[i] : wz;
            }
            // key: [bv bits | norig(14) | wid(4) | bi(4)]
            const unsigned lo = ((bk >> 5) << 16) | ((unsigned)wid << 4) | ((bk & 31u) - 1u);
            const unsigned long long ww =
                ((unsigned long long)__float_as_uint(bv) << 32) | lo;
            bkey = ww;

            unsigned long long w = ww;
#pragma unroll
            for (int off = 32; off >= 1; off >>= 1) {
                unsigned long long o = shfl_xor_u64(w, off);
                if (o > w) w = o;
            }
            if (ww == w) {                        // unique owner lane
                const unsigned bi = (bk & 31u) - 1u;
                float wx = xs[bi * 1024 + tid];   // runtime LDS index: fine
                wkeys[wid]  = w;
                wcoord[wid] = make_float4(wx, wy, wz, 0.f);
            }
        }
        __syncthreads();                          // barrier A: publishes visible

        unsigned long long k2 = wkeys[lane & 15];
#pragma unroll
        for (int off = 8; off >= 1; off >>= 1) {
            unsigned long long o = shfl_xor_u64(k2, off);
            if (o > k2) k2 = o;
        }
        const unsigned kl = (unsigned)k2;
        const int winw = (int)((kl >> 4) & 15u);
        const float4 wc = wcoord[winw];           // broadcast LDS read
        cx = wc.x; cy = wc.y; cz = wc.z;
        if (tid == 0) {
            const int orig = 16383 - (int)(kl >> 16);
            idxf_out[b * M_CENT + j] = (float)orig;
            newxyz_out[(b * M_CENT + j) * 3 + 0] = cx;
            newxyz_out[(b * M_CENT + j) * 3 + 1] = cy;
            newxyz_out[(b * M_CENT + j) * 3 + 2] = cz;
        }
        __syncthreads();                          // barrier B: reads done before
                                                  // next iteration's writes
    }
}

// ---------------------------------------------------------------------------
__global__ __launch_bounds__(256) void ball_kernel(
    const float* __restrict__ xyz,
    const float* __restrict__ newxyz,
    int* __restrict__ nidx)
{
#pragma clang fp contract(off)
    const float R2 = (float)(0.1 * 0.1);
    const int gw   = blockIdx.x * 4 + (threadIdx.x >> 6);
    const int lane = threadIdx.x & 63;
    const int b    = gw >> 10;
    const float* P = xyz + (size_t)b * N_PTS * 3;
    const float cx = newxyz[gw * 3 + 0];
    const float cy = newxyz[gw * 3 + 1];
    const float cz = newxyz[gw * 3 + 2];
    int* out = nidx + gw * K_SMP;

    int cnt = 0, first = -1;
    for (int base = 0; base < N_PTS; base += 64) {
        const int n = base + lane;
        float dx = P[n * 3 + 0] - cx;
        float dy = P[n * 3 + 1] - cy;
        float dz = P[n * 3 + 2] - cz;
        float xx = dx * dx, yy = dy * dy, zz = dz * dz;
        float d2 = (xx + yy) + zz;
        bool inb = d2 < R2;
        unsigned long long mask = __ballot(inb);
        if (mask) {
            if (first < 0) first = base + __ffsll(mask) - 1;
            int before = __popcll(mask & ((1ull << lane) - 1ull));
            int slot = cnt + before;
            if (inb && slot < K_SMP) out[slot] = n;
            cnt += __popcll(mask);
            if (cnt >= K_SMP) break;
        }
    }
    for (int s = cnt + lane; s < K_SMP; s += 64) out[s] = first;
}

// ---------------------------------------------------------------------------
// Weight prep: f32 (OC,IC) -> bf16 (OC,ICP). remap=1 reorders input channels
// from [xyz(3), feat(64)] to [feat(64), xyz(3), pad] to match Xt layout.
__global__ void prep_w(const float* __restrict__ src, short* __restrict__ dst,
                       int OC, int IC, int ICP, int remap)
{
    int i = blockIdx.x * 256 + threadIdx.x;
    if (i >= OC * ICP) return;
    int oc = i / ICP, ic = i - oc * ICP;
    float v = 0.0f;
    if (remap) {
        if (ic < 64)      v = src[oc * IC + 3 + ic];
        else if (ic < 67) v = src[oc * IC + (ic - 64)];
    } else if (ic < IC)   v = src[oc * IC + ic];
    dst[i] = f2bf(v);
}

// feat (B,64,N) -> featT (B,N,64)
__global__ __launch_bounds__(256) void tfeat_kernel(
    const float* __restrict__ feat, float* __restrict__ featT)
{
    __shared__ float t[64][65];
    const int b = blockIdx.y;
    const int n0 = blockIdx.x * 64;
    for (int it = 0; it < 16; ++it) {
        int idx = it * 256 + threadIdx.x;
        int c = idx >> 6, n = idx & 63;
        t[c][n] = feat[((size_t)b * 64 + c) * N_PTS + n0 + n];
    }
    __syncthreads();
    for (int it = 0; it < 16; ++it) {
        int idx = it * 256 + threadIdx.x;
        int n = idx >> 6, c = idx & 63;
        featT[((size_t)b * N_PTS + n0 + n) * 64 + c] = t[c][n];
    }
}

// ---------------------------------------------------------------------------
// MFMA MLP: 64 cols (2 centroids) per block, 4 waves, bf16 16x16x32 MFMA.
__global__ __launch_bounds__(256, 2) void mlp_kernel(
    const float* __restrict__ xyz, const float* __restrict__ feat,
    const float* __restrict__ featT, int useT,
    const float* __restrict__ newxyz, const int* __restrict__ nidx,
    const short* __restrict__ WaB, const float* __restrict__ ba,
    const short* __restrict__ WbB, const float* __restrict__ bb,
    const short* __restrict__ WsB, const float* __restrict__ bs,
    const short* __restrict__ WcB, const float* __restrict__ bc,
    const short* __restrict__ WdB, const float* __restrict__ bd,
    float* __restrict__ pooled)
{
    __shared__ short Xt[64][104];
    __shared__ short Ht[64][136];
    __shared__ short Tt[64][136];

    const int tid = threadIdx.x;
    const int w = tid >> 6, l = tid & 63, l16 = l & 15, kg = l >> 4;
    const int cen0 = blockIdx.x * 2;
    const int b = cen0 >> 10;
    const int ocw = 32 * w;

    {
        const int col = tid >> 2, part = tid & 3;
        const int ci = cen0 + (col >> 5);
        const int nn = nidx[ci * K_SMP + (col & 31)];
        float v[16];
        if (useT) {
            const f32x4* src = (const f32x4*)(featT + ((size_t)b * N_PTS + nn) * 64 + part * 16);
            f32x4 f0 = src[0], f1 = src[1], f2 = src[2], f3 = src[3];
            v[0]=f0[0]; v[1]=f0[1]; v[2]=f0[2]; v[3]=f0[3];
            v[4]=f1[0]; v[5]=f1[1]; v[6]=f1[2]; v[7]=f1[3];
            v[8]=f2[0]; v[9]=f2[1]; v[10]=f2[2]; v[11]=f2[3];
            v[12]=f3[0]; v[13]=f3[1]; v[14]=f3[2]; v[15]=f3[3];
        } else {
            const float* F = feat + (size_t)b * C_FEAT * N_PTS + nn;
#pragma unroll
            for (int q = 0; q < 16; ++q) v[q] = F[(size_t)(part * 16 + q) * N_PTS];
        }
        bf16x8 h0, h1;
#pragma unroll
        for (int q = 0; q < 8; ++q) { h0[q] = f2bf(v[q]); h1[q] = f2bf(v[q + 8]); }
        *(bf16x8*)&Xt[col][part * 16]     = h0;
        *(bf16x8*)&Xt[col][part * 16 + 8] = h1;
        if (part == 0) {
            bf16x8 hx, zv;
#pragma unroll
            for (int q = 0; q < 8; ++q) { hx[q] = 0; zv[q] = 0; }
            hx[0] = f2bf(xyz[((size_t)b * N_PTS + nn) * 3 + 0] - newxyz[ci * 3 + 0]);
            hx[1] = f2bf(xyz[((size_t)b * N_PTS + nn) * 3 + 1] - newxyz[ci * 3 + 1]);
            hx[2] = f2bf(xyz[((size_t)b * N_PTS + nn) * 3 + 2] - newxyz[ci * 3 + 2]);
            *(bf16x8*)&Xt[col][64] = hx;
            *(bf16x8*)&Xt[col][72] = zv;
            *(bf16x8*)&Xt[col][80] = zv;
            *(bf16x8*)&Xt[col][88] = zv;
        }
    }
    __syncthreads();

    f32x4 accA[2][4], accS[2][4];
#pragma unroll
    for (int o = 0; o < 2; ++o)
#pragma unroll
        for (int ct = 0; ct < 4; ++ct) {
#pragma unroll
            for (int r = 0; r < 4; ++r) { accA[o][ct][r] = 0.f; accS[o][ct][r] = 0.f; }
        }
#pragma unroll
    for (int k = 0; k < 3; ++k) {
        bf16x8 xb[4];
#pragma unroll
        for (int ct = 0; ct < 4; ++ct)
            xb[ct] = *(const bf16x8*)&Xt[ct * 16 + l16][k * 32 + kg * 8];
#pragma unroll
        for (int o = 0; o < 2; ++o) {
            const int row = ocw + o * 16 + l16;
            bf16x8 wa  = *(const bf16x8*)(WaB + row * 96 + k * 32 + kg * 8);
            bf16x8 wsv = *(const bf16x8*)(WsB + row * 96 + k * 32 + kg * 8);
#pragma unroll
            for (int ct = 0; ct < 4; ++ct) {
                accA[o][ct] = __builtin_amdgcn_mfma_f32_16x16x32_bf16(wa,  xb[ct], accA[o][ct], 0, 0, 0);
                accS[o][ct] = __builtin_amdgcn_mfma_f32_16x16x32_bf16(wsv, xb[ct], accS[o][ct], 0, 0, 0);
            }
        }
    }
#pragma unroll
    for (int o = 0; o < 2; ++o) {
        const f32x4 bav = *(const f32x4*)(ba + ocw + o * 16 + kg * 4);
#pragma unroll
        for (int ct = 0; ct < 4; ++ct) {
            s16x4 hv;
#pragma unroll
            for (int r = 0; r < 4; ++r) hv[r] = f2bf(fmaxf(accA[o][ct][r] + bav[r], 0.f));
            *(s16x4*)&Ht[ct * 16 + l16][ocw + o * 16 + kg * 4] = hv;
        }
    }
    __syncthreads();

    f32x4 accB[2][4];
#pragma unroll
    for (int o = 0; o < 2; ++o)
#pragma unroll
        for (int ct = 0; ct < 4; ++ct) {
#pragma unroll
            for (int r = 0; r < 4; ++r) accB[o][ct][r] = 0.f;
        }
#pragma unroll
    for (int k = 0; k < 4; ++k) {
        bf16x8 xb[4];
#pragma unroll
        for (int ct = 0; ct < 4; ++ct)
            xb[ct] = *(const bf16x8*)&Ht[ct * 16 + l16][k * 32 + kg * 8];
#pragma unroll
        for (int o = 0; o < 2; ++o) {
            const int row = ocw + o * 16 + l16;
            bf16x8 wbv = *(const bf16x8*)(WbB + row * 128 + k * 32 + kg * 8);
#pragma unroll
            for (int ct = 0; ct < 4; ++ct)
                accB[o][ct] = __builtin_amdgcn_mfma_f32_16x16x32_bf16(wbv, xb[ct], accB[o][ct], 0, 0, 0);
        }
    }
    f32x4 hreg[2][4];
#pragma unroll
    for (int o = 0; o < 2; ++o) {
        const f32x4 bbv = *(const f32x4*)(bb + ocw + o * 16 + kg * 4);
        const f32x4 bsv = *(const f32x4*)(bs + ocw + o * 16 + kg * 4);
#pragma unroll
        for (int ct = 0; ct < 4; ++ct) {
#pragma unroll
            for (int r = 0; r < 4; ++r)
                hreg[o][ct][r] = fmaxf((accB[o][ct][r] + bbv[r]) + (accS[o][ct][r] + bsv[r]), 0.f);
        }
    }
    __syncthreads();
#pragma unroll
    for (int o = 0; o < 2; ++o)
#pragma unroll
        for (int ct = 0; ct < 4; ++ct) {
            s16x4 hv;
#pragma unroll
            for (int r = 0; r < 4; ++r) hv[r] = f2bf(hreg[o][ct][r]);
            *(s16x4*)&Ht[ct * 16 + l16][ocw + o * 16 + kg * 4] = hv;
        }
    __syncthreads();

    f32x4 accD[2][4];
#pragma unroll
    for (int o = 0; o < 2; ++o)
#pragma unroll
        for (int ct = 0; ct < 4; ++ct) {
#pragma unroll
            for (int r = 0; r < 4; ++r) accD[o][ct][r] = 0.f;
        }
    for (int cc = 0; cc < 4; ++cc) {
        f32x4 accC[2][4];
#pragma unroll
        for (int o = 0; o < 2; ++o)
#pragma unroll
            for (int ct = 0; ct < 4; ++ct) {
#pragma unroll
                for (int r = 0; r < 4; ++r) accC[o][ct][r] = 0.f;
            }
#pragma unroll
        for (int k = 0; k < 4; ++k) {
            bf16x8 xb[4];
#pragma unroll
            for (int ct = 0; ct < 4; ++ct)
                xb[ct] = *(const bf16x8*)&Ht[ct * 16 + l16][k * 32 + kg * 8];
#pragma unroll
            for (int o = 0; o < 2; ++o) {
                const int row = cc * 128 + ocw + o * 16 + l16;
                bf16x8 wcv = *(const bf16x8*)(WcB + row * 128 + k * 32 + kg * 8);
#pragma unroll
                for (int ct = 0; ct < 4; ++ct)
                    accC[o][ct] = __builtin_amdgcn_mfma_f32_16x16x32_bf16(wcv, xb[ct], accC[o][ct], 0, 0, 0);
            }
        }
        __syncthreads();
#pragma unroll
        for (int o = 0; o < 2; ++o) {
            const f32x4 bcv = *(const f32x4*)(bc + cc * 128 + ocw + o * 16 + kg * 4);
#pragma unroll
            for (int ct = 0; ct < 4; ++ct) {
                s16x4 tv;
#pragma unroll
                for (int r = 0; r < 4; ++r) tv[r] = f2bf(fmaxf(accC[o][ct][r] + bcv[r], 0.f));
                *(s16x4*)&Tt[ct * 16 + l16][ocw + o * 16 + kg * 4] = tv;
            }
        }
        __syncthreads();
#pragma unroll
        for (int k = 0; k < 4; ++k) {
            bf16x8 tb[4];
#pragma unroll
            for (int ct = 0; ct < 4; ++ct)
                tb[ct] = *(const bf16x8*)&Tt[ct * 16 + l16][k * 32 + kg * 8];
#pragma unroll
            for (int o = 0; o < 2; ++o) {
                const int row = ocw + o * 16 + l16;
                bf16x8 wdv = *(const bf16x8*)(WdB + row * 512 + cc * 128 + k * 32 + kg * 8);
#pragma unroll
                for (int ct = 0; ct < 4; ++ct)
                    accD[o][ct] = __builtin_amdgcn_mfma_f32_16x16x32_bf16(wdv, tb[ct], accD[o][ct], 0, 0, 0);
            }
        }
    }

    const int m0 = cen0 & 1023;
#pragma unroll
    for (int o = 0; o < 2; ++o) {
        const f32x4 bdv = *(const f32x4*)(bd + ocw + o * 16 + kg * 4);
#pragma unroll
        for (int r = 0; r < 4; ++r) {
            float a0 = fmaxf((accD[o][0][r] + bdv[r]) + hreg[o][0][r], 0.f);
            float a1 = fmaxf((accD[o][1][r] + bdv[r]) + hreg[o][1][r], 0.f);
            float a2 = fmaxf((accD[o][2][r] + bdv[r]) + hreg[o][2][r], 0.f);
            float a3 = fmaxf((accD[o][3][r] + bdv[r]) + hreg[o][3][r], 0.f);
            float u0 = fmaxf(a0, a1), u1 = fmaxf(a2, a3);
#pragma unroll
            for (int off = 1; off < 16; off <<= 1) {
                u0 = fmaxf(u0, __shfl_xor(u0, off));
                u1 = fmaxf(u1, __shfl_xor(u1, off));
            }
            if (l16 == 0) {
                const int oc = ocw + o * 16 + kg * 4 + r;
                pooled[((size_t)b * 128 + oc) * 1024 + m0]     = u0;
                pooled[((size_t)b * 128 + oc) * 1024 + m0 + 1] = u1;
            }
        }
    }
}

// ---------------------------------------------------------------------------
extern "C" void kernel_launch(void* const* d_in, const int* in_sizes, int n_in,
                              void* d_out, int out_size, void* d_ws, size_t ws_size,
                              hipStream_t stream)
{
    const float* xyz  = (const float*)d_in[0];
    const float* feat = (const float*)d_in[1];
    const float* Wa = (const float*)d_in[2];   const float* ba = (const float*)d_in[3];
    const float* Wb = (const float*)d_in[4];   const float* bb = (const float*)d_in[5];
    const float* Ws = (const float*)d_in[6];   const float* bs = (const float*)d_in[7];
    const float* Wc = (const float*)d_in[8];   const float* bc = (const float*)d_in[9];
    const float* Wd = (const float*)d_in[10];  const float* bd = (const float*)d_in[11];

    float* out    = (float*)d_out;
    float* newxyz = out;
    float* pooled = out + 4 * 1024 * 3;
    float* idxf   = pooled + 4 * 128 * 1024;

    char* ws = (char*)d_ws;
    float4* gsxyz = (float4*)ws;                 // 1 MiB; reused as nidx after fps
    int*    nidx  = (int*)ws;
    short* WaB = (short*)(ws + (1 << 20));       // 128*96
    short* WsB = WaB + 128 * 96;                 // 128*96
    short* WbB = WsB + 128 * 96;                 // 128*128
    short* WcB = WbB + 128 * 128;                // 512*128
    short* WdB = WcB + 512 * 128;                // 128*512
    int*   ghist = (int*)(WdB + 128 * 512);
    int*   gbase = ghist + 4 * NCELL;
    float* featT = (float*)(ws + (2 << 20));     // 16 MiB, optional

    const size_t need = (size_t)(2 << 20) + (size_t)4 * N_PTS * 64 * 4;
    const int useT = (ws_size >= need) ? 1 : 0;

    prep_w<<<(128 *  96 + 255) / 256, 256, 0, stream>>>(Wa, WaB, 128,  67,  96, 1);
    prep_w<<<(128 *  96 + 255) / 256, 256, 0, stream>>>(Ws, WsB, 128,  67,  96, 1);
    prep_w<<<(128 * 128 + 255) / 256, 256, 0, stream>>>(Wb, WbB, 128, 128, 128, 0);
    prep_w<<<(512 * 128 + 255) / 256, 256, 0, stream>>>(Wc, WcB, 512, 128, 128, 0);
    prep_w<<<(128 * 512 + 255) / 256, 256, 0, stream>>>(Wd, WdB, 128, 512, 512, 0);
    if (useT) tfeat_kernel<<<dim3(N_PTS / 64, 4), 256, 0, stream>>>(feat, featT);

    hist_kernel   <<<4, 1024,  0, stream>>>(xyz, ghist);
    scan_kernel   <<<4, NCELL, 0, stream>>>(ghist, gbase);
    scatter_kernel<<<4, 1024,  0, stream>>>(xyz, gbase, gsxyz);

    fps_kernel<<<4, 1024, 0, stream>>>(xyz, gsxyz, newxyz, idxf);
    ball_kernel<<<1024, 256, 0, stream>>>(xyz, newxyz, nidx);
    mlp_kernel<<<2048, 256, 0, stream>>>(xyz, feat, featT, useT, newxyz, nidx,
                                         WaB, ba, WbB, bb, WsB, bs,
                                         WcB, bc, WdB, bd, pooled);
}